// Round 1
// baseline (32.231 us; speedup 1.0000x reference)
//
#include <hip/hip_runtime.h>
#include <math.h>

#define MU 1e-4f
#define COUNT_EPS 1e-4f
#define TWO_PI_F 6.2831853071795864769f

constexpr int P = 8;    // partitions (reference: 8)
constexpr int N = 128;  // neighbors
// T = 8 timesteps, 2 coords -> 16 floats per neighbor

__global__ __launch_bounds__(128) void social_circle_kernel(
    const float* __restrict__ trajs,   // [B, 8, 2]
    const float* __restrict__ nei,     // [B, 128, 8, 2]
    float* __restrict__ social,        // [B, P, 3]
    float* __restrict__ fdir)          // [B, N]
{
    const int b = blockIdx.x;
    const int n = threadIdx.x;

    __shared__ float acc[P][4];   // {sum_speed, sum_dist, sum_dir, count}
    __shared__ float s_obs[3];    // {obs_len, last_x, last_y}

    if (threadIdx.x < P * 4) ((float*)acc)[threadIdx.x] = 0.0f;
    if (threadIdx.x == 0) {
        const float* tb = trajs + (size_t)b * 16;
        const float lx = tb[14], ly = tb[15];         // t=7
        const float ox = lx - tb[0], oy = ly - tb[1]; // t=7 - t=0
        s_obs[0] = sqrtf(ox * ox + oy * oy);
        s_obs[1] = lx;
        s_obs[2] = ly;
    }
    __syncthreads();

    const float obs_len = s_obs[0];
    const float lastx = s_obs[1], lasty = s_obs[2];

    // 64 contiguous bytes per neighbor -> 4x float4, fully coalesced
    const float4* np4 = (const float4*)(nei + ((size_t)b * N + n) * 16);
    const float4 v0 = np4[0], v1 = np4[1], v2 = np4[2], v3 = np4[3];

    // validity mask: sum over all 16 values != 0
    const float msum = v0.x + v0.y + v0.z + v0.w
                     + v1.x + v1.y + v1.z + v1.w
                     + v2.x + v2.y + v2.z + v2.w
                     + v3.x + v3.y + v3.z + v3.w;

    const float fx = v0.x, fy = v0.y;  // t=0
    const float ex = v3.z, ey = v3.w;  // t=7

    const float nvx = ex - fx, nvy = ey - fy;
    const float nei_len = sqrtf(nvx * nvx + nvy * nvy);
    const float f_speed = (nei_len + MU) / (obs_len + MU);

    const float px = ex - lastx, py = ey - lasty;
    const float f_dist = sqrtf(px * px + py * py);

    float d = atan2f(py, px);
    if (d < 0.0f) d += (float)TWO_PI_F;   // == jnp.mod(atan2, 2*pi) on [-pi,pi]

    fdir[(size_t)b * N + n] = d;

    // same float32 division as reference; idx==P (d rounded up to 2*pi)
    // behaves like one_hot out-of-range: excluded.
    const float step = (float)(TWO_PI_F / P);
    const int idx = (int)(d / step);
    const bool valid = (msum != 0.0f) && (idx >= 0) && (idx < P);
    if (valid) {
        atomicAdd(&acc[idx][0], f_speed);
        atomicAdd(&acc[idx][1], f_dist);
        atomicAdd(&acc[idx][2], d);
        atomicAdd(&acc[idx][3], 1.0f);
    }
    __syncthreads();

    if (threadIdx.x < P * 3) {
        const int p = threadIdx.x / 3, f = threadIdx.x % 3;
        social[(size_t)b * (P * 3) + threadIdx.x] = acc[p][f] / (acc[p][3] + COUNT_EPS);
    }
}

extern "C" void kernel_launch(void* const* d_in, const int* in_sizes, int n_in,
                              void* d_out, int out_size, void* d_ws, size_t ws_size,
                              hipStream_t stream) {
    const float* trajs = (const float*)d_in[0];
    const float* nei   = (const float*)d_in[1];
    // d_in[2] = partitions (device scalar) — reference fixes it at 8.

    const int B = in_sizes[0] / 16;  // trajs is [B, 8, 2]

    float* social = (float*)d_out;              // [B, 8, 3]
    float* fdir   = (float*)d_out + (size_t)B * P * 3;  // [B, 128]

    social_circle_kernel<<<B, N, 0, stream>>>(trajs, nei, social, fdir);
}